// Round 1
// 244.213 us; speedup vs baseline: 1.0006x; 1.0006x over previous
//
#include <hip/hip_runtime.h>

// Problem constants (match reference)
constexpr int B = 8, C = 256, H = 96, W = 96;
constexpr int HW = H * W;          // 9216
constexpr int NPIX = B * HW;       // 73728
constexpr int PATCH = 21;
constexpr int HALF = PATCH / 2;    // 10
constexpr int DIL = 2;
constexpr int P2 = PATCH * PATCH;  // 441

// ---------------------------------------------------------------------------
// Stage 1: D[b,y,x] = sum_c in1[b,c,y,x] * in2[b,c,y,x]
//
// Previous version: 1 thread per pixel, 256-deep channel loop -> only 288
// workgroups (1.125 waves/SIMD), 2:1 CU load imbalance, and outstanding-bytes
// right at the latency-hiding threshold. HBM-bound floor was ~43 us.
//
// New version: block of 256 threads = 4 waves. Wave w owns channels
// [64w, 64w+64); lane l owns pixel chunk*64+l (64 consecutive pixels -> fully
// coalesced 256B per load instruction). Cross-wave LDS reduce at the end.
// -> 1152 workgroups (18 waves/CU), imbalance 5/4.5 = 1.11x, ~4x outstanding
// bytes per CU. Expect ~26-32 us (151 MB read).
// ---------------------------------------------------------------------------
constexpr int CHUNKS_PER_B = HW / 64;   // 144 chunks of 64 pixels per batch

__global__ __launch_bounds__(256) void dot_kernel(const float* __restrict__ a,
                                                  const float* __restrict__ b,
                                                  float* __restrict__ D) {
    __shared__ float red[256];
    const int l = threadIdx.x & 63;          // lane -> pixel within chunk
    const int w = threadIdx.x >> 6;          // wave -> channel group (0..3)
    const int blk = blockIdx.x;              // 0..1151
    const int bb = blk / CHUNKS_PER_B;
    const int chunk = blk - bb * CHUNKS_PER_B;
    const int hw = chunk * 64 + l;

    const float* pa = a + ((size_t)bb * C + (size_t)w * 64) * HW + hw;
    const float* pb = b + ((size_t)bb * C + (size_t)w * 64) * HW + hw;

    // 4 independent accumulators; unroll-4 over the c+=4 loop keeps ~32 loads
    // in flight per wave (8 KB/wave, ~144 KB/CU outstanding at 18 waves/CU).
    float s0 = 0.f, s1 = 0.f, s2 = 0.f, s3 = 0.f;
    #pragma unroll 4
    for (int c = 0; c < 64; c += 4) {
        float a0 = pa[0];
        float a1 = pa[(size_t)HW];
        float a2 = pa[(size_t)2 * HW];
        float a3 = pa[(size_t)3 * HW];
        float b0 = pb[0];
        float b1 = pb[(size_t)HW];
        float b2 = pb[(size_t)2 * HW];
        float b3 = pb[(size_t)3 * HW];
        pa += (size_t)4 * HW;
        pb += (size_t)4 * HW;
        s0 = fmaf(a0, b0, s0);
        s1 = fmaf(a1, b1, s1);
        s2 = fmaf(a2, b2, s2);
        s3 = fmaf(a3, b3, s3);
    }

    red[threadIdx.x] = (s0 + s1) + (s2 + s3);
    __syncthreads();
    if (w == 0) {
        float r = (red[l] + red[l + 64]) + (red[l + 128] + red[l + 192]);
        D[(size_t)bb * HW + hw] = r;   // 64-lane coalesced 256B store
    }
}

// ---------------------------------------------------------------------------
// Stage 2: out[b, py*21+px, y, x] = D[b, y+(py-10)*2, x+(px-10)*2] (0 if OOB)
//
// 3D grid (x = H*W4/256 = 9, y = P2 = 441, z = B = 8) makes p and b
// block-uniform (scalar-unit math: py = p/21 etc.), leaving a single
// magic-div by 24 per thread. Stores: 1 float4/thread, wave writes 1 KB
// contiguous. D reads are cache-resident (295 KB total).
// ---------------------------------------------------------------------------
__global__ __launch_bounds__(256) void scatter_kernel(const float* __restrict__ D,
                                                      float* __restrict__ out) {
    constexpr int W4 = W / 4;                 // 24
    const int t = blockIdx.x * 256 + threadIdx.x;   // 0..2303 (y*24 + x4)
    const int y  = t / W4;
    const int x4 = t - y * W4;
    const int p  = blockIdx.y;                // uniform
    const int bb = blockIdx.z;                // uniform

    const int py = p / PATCH;                 // uniform -> scalar div
    const int px = p - py * PATCH;
    const int sy  = y + (py - HALF) * DIL;
    const int sx0 = x4 * 4 + (px - HALF) * DIL;   // always even -> 8B aligned

    float4 v = make_float4(0.f, 0.f, 0.f, 0.f);
    if ((unsigned)sy < (unsigned)H) {
        const float* row = D + ((size_t)bb * H + sy) * W;
        if (sx0 >= 0 && sx0 + 3 < W) {
            // fully in-bounds: two aligned float2 loads
            float2 lo = *(const float2*)(row + sx0);
            float2 hi = *(const float2*)(row + sx0 + 2);
            v = make_float4(lo.x, lo.y, hi.x, hi.y);
        } else {
            float* pv = &v.x;
            #pragma unroll
            for (int i = 0; i < 4; ++i) {
                int sx = sx0 + i;
                if ((unsigned)sx < (unsigned)W) pv[i] = row[sx];
            }
        }
    }

    const size_t o = (size_t)(bb * P2 + p) * (H * W4) + t;
    reinterpret_cast<float4*>(out)[o] = v;
}

extern "C" void kernel_launch(void* const* d_in, const int* in_sizes, int n_in,
                              void* d_out, int out_size, void* d_ws, size_t ws_size,
                              hipStream_t stream) {
    const float* in1 = (const float*)d_in[0];
    const float* in2 = (const float*)d_in[1];
    float* out = (float*)d_out;
    float* D = (float*)d_ws;  // NPIX floats = 294,912 bytes

    {
        // 1152 blocks: 8 batches x 144 chunks of 64 pixels
        dot_kernel<<<B * CHUNKS_PER_B, 256, 0, stream>>>(in1, in2, D);
    }
    {
        // (H*W4)/256 = 9 blocks along x, 441 patch offsets, 8 batches
        scatter_kernel<<<dim3((H * (W / 4)) / 256, P2, B), 256, 0, stream>>>(D, out);
    }
}

// Round 3
// 241.547 us; speedup vs baseline: 1.0116x; 1.0110x over previous
//
#include <hip/hip_runtime.h>

// Problem constants (match reference)
constexpr int B = 8, C = 256, H = 96, W = 96;
constexpr int HW = H * W;          // 9216
constexpr int NPIX = B * HW;       // 73728
constexpr int PATCH = 21;
constexpr int HALF = PATCH / 2;    // 10
constexpr int DIL = 2;
constexpr int P2 = PATCH * PATCH;  // 441

// Native 4-float vector for nontemporal builtins (HIP's float4 is a class
// type that __builtin_nontemporal_store rejects).
typedef float f32x4 __attribute__((ext_vector_type(4)));

// Padded-D geometry: D lives at origin (PADR, PADR) inside a [PH][PW] image,
// pads are zero -> scatter is branchless and always in-bounds.
constexpr int PADR = 2 * HALF;          // 20 (max shift magnitude)
constexpr int PH = H + 2 * PADR;        // 136
constexpr int PW = 144;                 // >= 96+40=136, 16B-multiple stride
constexpr size_t DP_BYTES = (size_t)B * PH * PW * 4;   // 626,688 B

constexpr int CHUNKS_PER_B = HW / 64;            // 144
constexpr int DOT_BLOCKS = B * CHUNKS_PER_B;     // 1152
constexpr int PADCELLS_PER_B = PH * PW - H * W;  // 19584-9216 = 10368
constexpr int PAD_BLOCKS = (B * PADCELLS_PER_B) / 256;  // 82944/256 = 324
static_assert((B * PADCELLS_PER_B) % 256 == 0, "pad cells must tile by 256");

// ---------------------------------------------------------------------------
// Stage 1 (padded): D[b,y,x] = sum_c in1[b,c,y,x]*in2[b,c,y,x], written into
// the padded image; 324 extra blocks zero the pad cells (disjoint addresses,
// so no intra-kernel race). Memory structure of the dot itself is UNCHANGED
// from round 1 (it is at its HBM floor ~25us) -- only the store address
// changed (still <=2 contiguous segments per wave; stores are 0.3 MB total).
// ---------------------------------------------------------------------------
__global__ __launch_bounds__(256) void dot_pad_kernel(const float* __restrict__ a,
                                                      const float* __restrict__ b,
                                                      float* __restrict__ Dp) {
    const int blk = blockIdx.x;
    if (blk >= DOT_BLOCKS) {
        // ---- pad-zero job: enumerate the 10368 pad cells per batch image ----
        // regions per b: top 20x144=2880, bottom 20x144=2880,
        //                left 96x20=1920, right 96x28=2688  (total 10368)
        int idx = (blk - DOT_BLOCKS) * 256 + threadIdx.x;   // 0..82943
        int bb = idx / PADCELLS_PER_B;
        int r2 = idx - bb * PADCELLS_PER_B;
        int r, c;
        if (r2 < 2880)        { r = r2 / PW;                c = r2 - r * PW; }
        else if (r2 < 5760)   { int t = r2 - 2880; int q = t / PW;
                                r = (PADR + H) + q;         c = t - q * PW; }
        else if (r2 < 7680)   { int t = r2 - 5760; int q = t / PADR;
                                r = PADR + q;               c = t - q * PADR; }
        else                  { int t = r2 - 7680; int q = t / 28;
                                r = PADR + q;               c = (PADR + H) + (t - q * 28); }
        Dp[((size_t)bb * PH + r) * PW + c] = 0.f;
        return;
    }

    __shared__ float red[256];
    const int l = threadIdx.x & 63;          // lane -> pixel within chunk
    const int w = threadIdx.x >> 6;          // wave -> channel group (0..3)
    const int bb = blk / CHUNKS_PER_B;
    const int chunk = blk - bb * CHUNKS_PER_B;
    const int hw = chunk * 64 + l;

    const float* pa = a + ((size_t)bb * C + (size_t)w * 64) * HW + hw;
    const float* pb = b + ((size_t)bb * C + (size_t)w * 64) * HW + hw;

    float s0 = 0.f, s1 = 0.f, s2 = 0.f, s3 = 0.f;
    #pragma unroll 4
    for (int c = 0; c < 64; c += 4) {
        float a0 = pa[0];
        float a1 = pa[(size_t)HW];
        float a2 = pa[(size_t)2 * HW];
        float a3 = pa[(size_t)3 * HW];
        float b0 = pb[0];
        float b1 = pb[(size_t)HW];
        float b2 = pb[(size_t)2 * HW];
        float b3 = pb[(size_t)3 * HW];
        pa += (size_t)4 * HW;
        pb += (size_t)4 * HW;
        s0 = fmaf(a0, b0, s0);
        s1 = fmaf(a1, b1, s1);
        s2 = fmaf(a2, b2, s2);
        s3 = fmaf(a3, b3, s3);
    }

    red[threadIdx.x] = (s0 + s1) + (s2 + s3);
    __syncthreads();
    if (w == 0) {
        const int y = hw / W;
        const int x = hw - y * W;
        float r = (red[l] + red[l + 64]) + (red[l + 128] + red[l + 192]);
        Dp[((size_t)bb * PH + (PADR + y)) * PW + (PADR + x)] = r;
    }
}

// ---------------------------------------------------------------------------
// Stage 2 (padded, branchless): out[b, py*21+px, y, x] = Dp[b, y+2*py, x+2*px]
// No bounds checks at all (pads are zero). Nontemporal float4 stores: the
// 130 MB output stream is write-once -> keep it out of L2 writeback thrash.
// Reads are cache-resident (Dp = 612 KB total).
// ---------------------------------------------------------------------------
__global__ __launch_bounds__(256) void scatter_pad_kernel(const float* __restrict__ Dp,
                                                          float* __restrict__ out) {
    constexpr int W4 = W / 4;                 // 24
    const int t = blockIdx.x * 256 + threadIdx.x;   // 0..2303 (y*24 + x4)
    const int y  = t / W4;
    const int x4 = t - y * W4;
    const int p  = blockIdx.y;                // uniform
    const int bb = blockIdx.z;                // uniform

    const int py = p / PATCH;                 // uniform -> scalar
    const int px = p - py * PATCH;
    const int sy = y + py * DIL;              // padded row index, always valid
    const int sx = x4 * 4 + px * DIL;         // padded col, even -> 8B aligned

    const float* row = Dp + ((size_t)bb * PH + sy) * PW + sx;
    float2 lo = *(const float2*)(row);
    float2 hi = *(const float2*)(row + 2);
    f32x4 v = { lo.x, lo.y, hi.x, hi.y };

    f32x4* dst = reinterpret_cast<f32x4*>(out) + ((size_t)(bb * P2 + p) * (H * W4) + t);
    __builtin_nontemporal_store(v, dst);
}

// ---------------------------------------------------------------------------
// Fallback path (ws too small for padded D): round-1 kernels, compact D.
// ---------------------------------------------------------------------------
__global__ __launch_bounds__(256) void dot_kernel(const float* __restrict__ a,
                                                  const float* __restrict__ b,
                                                  float* __restrict__ D) {
    __shared__ float red[256];
    const int l = threadIdx.x & 63;
    const int w = threadIdx.x >> 6;
    const int blk = blockIdx.x;
    const int bb = blk / CHUNKS_PER_B;
    const int chunk = blk - bb * CHUNKS_PER_B;
    const int hw = chunk * 64 + l;

    const float* pa = a + ((size_t)bb * C + (size_t)w * 64) * HW + hw;
    const float* pb = b + ((size_t)bb * C + (size_t)w * 64) * HW + hw;

    float s0 = 0.f, s1 = 0.f, s2 = 0.f, s3 = 0.f;
    #pragma unroll 4
    for (int c = 0; c < 64; c += 4) {
        float a0 = pa[0];
        float a1 = pa[(size_t)HW];
        float a2 = pa[(size_t)2 * HW];
        float a3 = pa[(size_t)3 * HW];
        float b0 = pb[0];
        float b1 = pb[(size_t)HW];
        float b2 = pb[(size_t)2 * HW];
        float b3 = pb[(size_t)3 * HW];
        pa += (size_t)4 * HW;
        pb += (size_t)4 * HW;
        s0 = fmaf(a0, b0, s0);
        s1 = fmaf(a1, b1, s1);
        s2 = fmaf(a2, b2, s2);
        s3 = fmaf(a3, b3, s3);
    }

    red[threadIdx.x] = (s0 + s1) + (s2 + s3);
    __syncthreads();
    if (w == 0) {
        float r = (red[l] + red[l + 64]) + (red[l + 128] + red[l + 192]);
        D[(size_t)bb * HW + hw] = r;
    }
}

__global__ __launch_bounds__(256) void scatter_kernel(const float* __restrict__ D,
                                                      float* __restrict__ out) {
    constexpr int W4 = W / 4;
    const int t = blockIdx.x * 256 + threadIdx.x;
    const int y  = t / W4;
    const int x4 = t - y * W4;
    const int p  = blockIdx.y;
    const int bb = blockIdx.z;

    const int py = p / PATCH;
    const int px = p - py * PATCH;
    const int sy  = y + (py - HALF) * DIL;
    const int sx0 = x4 * 4 + (px - HALF) * DIL;

    float4 v = make_float4(0.f, 0.f, 0.f, 0.f);
    if ((unsigned)sy < (unsigned)H) {
        const float* row = D + ((size_t)bb * H + sy) * W;
        if (sx0 >= 0 && sx0 + 3 < W) {
            float2 lo = *(const float2*)(row + sx0);
            float2 hi = *(const float2*)(row + sx0 + 2);
            v = make_float4(lo.x, lo.y, hi.x, hi.y);
        } else {
            float* pv = &v.x;
            #pragma unroll
            for (int i = 0; i < 4; ++i) {
                int sx = sx0 + i;
                if ((unsigned)sx < (unsigned)W) pv[i] = row[sx];
            }
        }
    }
    const size_t o = (size_t)(bb * P2 + p) * (H * W4) + t;
    reinterpret_cast<float4*>(out)[o] = v;
}

extern "C" void kernel_launch(void* const* d_in, const int* in_sizes, int n_in,
                              void* d_out, int out_size, void* d_ws, size_t ws_size,
                              hipStream_t stream) {
    const float* in1 = (const float*)d_in[0];
    const float* in2 = (const float*)d_in[1];
    float* out = (float*)d_out;

    if (ws_size >= DP_BYTES) {
        float* Dp = (float*)d_ws;
        // dot blocks + pad-zero blocks in one launch (disjoint writes)
        dot_pad_kernel<<<DOT_BLOCKS + PAD_BLOCKS, 256, 0, stream>>>(in1, in2, Dp);
        scatter_pad_kernel<<<dim3((H * (W / 4)) / 256, P2, B), 256, 0, stream>>>(Dp, out);
    } else {
        float* D = (float*)d_ws;  // NPIX floats = 294,912 bytes
        dot_kernel<<<B * CHUNKS_PER_B, 256, 0, stream>>>(in1, in2, D);
        scatter_kernel<<<dim3((H * (W / 4)) / 256, P2, B), 256, 0, stream>>>(D, out);
    }
}